// Round 1
// 1567.201 us; speedup vs baseline: 1.2782x; 1.2782x over previous
//
#include <hip/hip_runtime.h>
#include <stdint.h>

#define NUM_IT 64
#define BATCH 64
#define HW 50176            // 224*224
#define CHW 150528          // 3*HW
#define SIGMA 0.05f

// ---- Circle staging -------------------------------------------------------
// Per pixel, the 3 zero-sum normalized channel perturbations are exactly
//   s_ch = QR8 * cos(phi - ch*2pi/3)   (one phase phi per pixel),
// since the zero-sum Gaussian direction is uniform on a circle. We store the
// circle point in 10 bits/px: 8-bit quantization of the smaller-magnitude
// coordinate m = min(|cos|,|sin|) (signed), a which-bit, and the sign of the
// other coordinate. |d(other)/d(m)| <= 1, so worst-case per-channel error is
// QR8*sqrt(2)*step/2 = 2.26e-4 — identical to the previous 2-channel u8
// scheme, at 10 bits/px instead of 16. 64 units * 4.01 MB = 257 MB fits the
// ~289 MB workspace (proven by the previous k=45 at 8 B) -> zero regen.
#define QR8 0.057735027f          // sigma*2/sqrt(3) = channel amplitude
#define ENC_SCALE 180.312f        // maps m in [-0.7071,0.7071] -> [0,255]
#define ENC_BIAS  127.5003f
#define DEC_STEP  5.5459533e-3f   // 1/ENC_SCALE
#define DEC_BIAS  (-0.70433384f)  // DEC_STEP/2 - 0.7071068 (midpoint decode)
// per (unit,b): IDX_PER_UB*(4+1) bytes; per unit: 12544*5*64 = 4,014,080 B
#define IDX_PER_UB 12544
#define WS_FLOATS ((NUM_IT + 1) * BATCH + BATCH * NUM_IT)   // 8256 floats

// ---------------- Threefry-2x32, 20 rounds (JAX-exact) ----------------
__device__ __forceinline__ void tf2x32(uint32_t k0, uint32_t k1,
                                       uint32_t x0, uint32_t x1,
                                       uint32_t &o0, uint32_t &o1) {
  const uint32_t ks2 = k0 ^ k1 ^ 0x1BD11BDAu;
  x0 += k0; x1 += k1;
#define TF_R(r) { x0 += x1; x1 = __builtin_amdgcn_alignbit(x1, x1, 32u - (r)); x1 ^= x0; }
  TF_R(13) TF_R(15) TF_R(26) TF_R(6)
  x0 += k1;  x1 += ks2 + 1u;
  TF_R(17) TF_R(29) TF_R(16) TF_R(24)
  x0 += ks2; x1 += k0 + 2u;
  TF_R(13) TF_R(15) TF_R(26) TF_R(6)
  x0 += k0;  x1 += k1 + 3u;
  TF_R(17) TF_R(29) TF_R(16) TF_R(24)
  x0 += k1;  x1 += ks2 + 4u;
  TF_R(13) TF_R(15) TF_R(26) TF_R(6)
  x0 += ks2; x1 += k0 + 5u;
#undef TF_R
  o0 = x0; o1 = x1;
}

// bits -> uniform(-0.99999994, 1) -> sqrt(2)*erfinv (XLA/Giles f32 poly).
__device__ __forceinline__ float bits_to_normal(uint32_t bits) {
  const float LO = __uint_as_float(0xBF7FFFFFu);     // nextafter(-1,0)
  float u01 = __uint_as_float((bits >> 9) | 0x3f800000u) - 1.0f;  // [0,1)
  float u = fmaf(u01, 2.0f, LO);
  // 1 - round(u*u) is Sterbenz-exact; __fmul_rn blocks fp-contraction.
  float s = __fmul_rn(u, u);
  float w = -__logf(1.0f - s);
  float p;
  if (w < 5.0f) {
    float z = w - 2.5f;
    p = 2.81022636e-08f;
    p = fmaf(p, z, 3.43273939e-07f);
    p = fmaf(p, z, -3.5233877e-06f);
    p = fmaf(p, z, -4.39150654e-06f);
    p = fmaf(p, z, 0.00021858087f);
    p = fmaf(p, z, -0.00125372503f);
    p = fmaf(p, z, -0.00417768164f);
    p = fmaf(p, z, 0.246640727f);
    p = fmaf(p, z, 1.50140941f);
  } else {
    float z = __builtin_amdgcn_sqrtf(w) - 3.0f;      // fast sqrt: z err ~4e-7
    p = -0.000200214257f;
    p = fmaf(p, z, 0.000100950558f);
    p = fmaf(p, z, 0.00134934322f);
    p = fmaf(p, z, -0.00367342844f);
    p = fmaf(p, z, 0.00573950773f);
    p = fmaf(p, z, -0.0076224613f);
    p = fmaf(p, z, 0.00943887047f);
    p = fmaf(p, z, 1.00167406f);
    p = fmaf(p, z, 2.83297682f);
  }
  return 1.41421356237309515f * (p * u);
}

__device__ __forceinline__ float clip01(float x) {
  return __builtin_amdgcn_fmed3f(x, 0.0f, 1.0f);     // 1 inst, finite inputs
}

// Pass 1: grid (49, BATCH, 13). Block z=g handles ii-units 5g..5g+4
// (unit 64 == prob2, in group 12). Stages 10-bit phase codes for unit<k.
__global__ __launch_bounds__(256) void pass1_kernel(
    const float* __restrict__ imgs, const float* __restrict__ noise,
    const float* __restrict__ wv, float* __restrict__ dots,
    uint32_t* __restrict__ ts32, uint8_t* __restrict__ ts8, const int k)
{
  const int g = blockIdx.z;
  const int b = blockIdx.y;
  __shared__ uint32_t kxs[5], kys[5];
  if (threadIdx.x < 5) {
    const int u = 5 * g + threadIdx.x;
    if (u < NUM_IT) {
      uint32_t kx, ky;
      tf2x32(0u, 42u, 0u, (uint32_t)u, kx, ky);
      kxs[threadIdx.x] = kx; kys[threadIdx.x] = ky;
    }
  }
  __syncthreads();

  const int idx  = blockIdx.x * 256 + threadIdx.x;        // 0..12543
  const int hw   = idx * 4;                               // 4 contiguous elems
  const int ebhw = b * CHW + hw;

  float ba[3][4], wc[3][4];
#pragma unroll
  for (int ch = 0; ch < 3; ++ch) {
    float4 iv = *(const float4*)(imgs  + ebhw + ch * HW);
    float4 nv = *(const float4*)(noise + ebhw + ch * HW);
    float4 wvv = *(const float4*)(wv   + hw   + ch * HW);
    ba[ch][0] = iv.x + nv.x; ba[ch][1] = iv.y + nv.y;
    ba[ch][2] = iv.z + nv.z; ba[ch][3] = iv.w + nv.w;
    wc[ch][0] = wvv.x; wc[ch][1] = wvv.y; wc[ch][2] = wvv.z; wc[ch][3] = wvv.w;
  }

#pragma unroll 1
  for (int u = 0; u < 5; ++u) {
    const int unit = 5 * g + u;       // 0..64; 64 == prob2
    if (unit > NUM_IT) break;
    float sum = 0.0f;
    if (unit == NUM_IT) {
#pragma unroll
      for (int ch = 0; ch < 3; ++ch)
#pragma unroll
        for (int j = 0; j < 4; ++j)
          sum = fmaf(clip01(ba[ch][j]), wc[ch][j], sum);
    } else {
      const uint32_t kx = kxs[u], ky = kys[u];
      uint32_t qa = 0, qb = 0;
#pragma unroll
      for (int j = 0; j < 4; ++j) {
        const uint32_t e = (uint32_t)(ebhw + j);
        uint32_t o0, o1;
        tf2x32(kx, ky, 0u, e,           o0, o1); float t0 = bits_to_normal(o0 ^ o1);
        tf2x32(kx, ky, 0u, e + HW,      o0, o1); float t1 = bits_to_normal(o0 ^ o1);
        tf2x32(kx, ky, 0u, e + 2u * HW, o0, o1); float t2 = bits_to_normal(o0 ^ o1);
        float mu = (t0 + t1 + t2) * (1.0f / 3.0f);
        float d0 = t0 - mu, d1 = t1 - mu, d2 = t2 - mu;
        float ss  = fmaf(d0, d0, fmaf(d1, d1, d2 * d2));    // = 2*var(ddof=1)
        float inv = __builtin_amdgcn_rsqf(ss);              // fast rsq ~1e-6
        float sc  = 0.070710678f * inv;                     // sigma*sqrt(2)
        sum = fmaf(clip01(fmaf(d0, sc, ba[0][j])), wc[0][j], sum);
        sum = fmaf(clip01(fmaf(d1, sc, ba[1][j])), wc[1][j], sum);
        sum = fmaf(clip01(fmaf(d2, sc, ba[2][j])), wc[2][j], sum);
        // encode: (cs,sn) = (cos phi, sin phi) of the pixel's phase
        float csc = 1.2247449f * inv;                       // sqrt(3/2)*inv
        float cs  = d0 * csc;
        float sn  = fmaf(d1, 1.4142136f * inv, 0.57735026f * cs);
        bool  wh  = __builtin_fabsf(sn) < __builtin_fabsf(cs);  // store sn?
        float m   = wh ? sn : cs;
        float oth = wh ? cs : sn;
        uint32_t q = (uint32_t)fmaf(m, ENC_SCALE, ENC_BIAS);    // cvt_u32 clamps neg
        uint32_t bits = q | (wh ? 256u : 0u) | (oth < 0.0f ? 512u : 0u);
        if (j < 3) qa |= bits << (10 * j);
        else       { qa |= bits << 30; qb = bits >> 2; }
      }
      if (unit < k) {
        const size_t base = (size_t)(unit * BATCH + b) * IDX_PER_UB + idx;
        ts32[base] = qa;
        ts8[base]  = (uint8_t)qb;
      }
    }
    for (int off = 32; off; off >>= 1) sum += __shfl_down(sum, off, 64);
    if ((threadIdx.x & 63) == 0) atomicAdd(&dots[unit * BATCH + b], sum);
  }
}

__global__ void coef_kernel(const float* __restrict__ dots,
                            const float* __restrict__ bptr,
                            float* __restrict__ coef) {
  const int b = threadIdx.x;  // 64 threads
  const float bias = bptr[0];
  const float p2 = 1.0f / (1.0f + expf(-(dots[NUM_IT * BATCH + b] + bias)));
  float nc = 0.0f;
  for (int i = 0; i < NUM_IT; ++i) {
    float ap = 1.0f / (1.0f + expf(-(dots[i * BATCH + b] + bias)));
    float d = p2 - ap;
    nc += d * d;
  }
  const float inv = 1.0f / ((float)NUM_IT * SIGMA * (sqrtf(nc) + 1e-10f));
  for (int i = 0; i < NUM_IT; ++i) {
    float ap = 1.0f / (1.0f + expf(-(dots[i * BATCH + b] + bias)));
    float d = p2 - ap;
    coef[b * NUM_IT + i] = d * inv;
  }
}

// Pass 2: grid (49, BATCH). Single writer per output element: decode all k
// staged units, regen any i>=k (expected none), plain float4 stores, no
// atomics, no out memset. ch2 = -(ch0+ch1).
__global__ __launch_bounds__(256) void pass2_kernel(
    float* __restrict__ out, const float* __restrict__ coef,
    const uint32_t* __restrict__ ts32, const uint8_t* __restrict__ ts8,
    const int k)
{
  const int b = blockIdx.y;
  __shared__ float cf[NUM_IT];
  __shared__ uint32_t kxs[NUM_IT], kys[NUM_IT];
  if (threadIdx.x < NUM_IT) {
    const int i = threadIdx.x;
    cf[i] = coef[b * NUM_IT + i];
    if (i >= k) {
      uint32_t kx, ky;
      tf2x32(0u, 42u, 0u, (uint32_t)i, kx, ky);
      kxs[i] = kx; kys[i] = ky;
    }
  }
  __syncthreads();

  const int idx  = blockIdx.x * 256 + threadIdx.x;
  const int hw   = idx * 4;
  const int ebhw = b * CHW + hw;
  float acc0[4] = {0.f, 0.f, 0.f, 0.f};
  float acc1[4] = {0.f, 0.f, 0.f, 0.f};

#pragma unroll 1
  for (int i = 0; i < k; ++i) {                    // staged units: decode
    const float ci = cf[i];
    const size_t base = (size_t)(i * BATCH + b) * IDX_PER_UB + idx;
    const uint32_t wa = ts32[base];
    const uint32_t wb = ts8[base];
#pragma unroll
    for (int j = 0; j < 4; ++j) {
      uint32_t bits = (j < 3) ? ((wa >> (10 * j)) & 1023u)
                              : ((wa >> 30) | (wb << 2));
      float m = fmaf((float)(bits & 255u), DEC_STEP, DEC_BIAS);
      m = __builtin_amdgcn_fmed3f(m, -0.7071068f, 0.7071068f);
      float o = __builtin_amdgcn_sqrtf(fmaf(-m, m, 1.0f));
      o = (bits & 512u) ? -o : o;
      const bool wh = (bits & 256u) != 0u;
      float cc = wh ? o : m;
      float sv = wh ? m : o;
      float s0 = QR8 * cc;
      float s1 = fmaf(sv, 0.05f, -0.5f * s0);      // QR8*sqrt(3)/2 == sigma
      acc0[j] = fmaf(s0, ci, acc0[j]);
      acc1[j] = fmaf(s1, ci, acc1[j]);
    }
  }
#pragma unroll 1
  for (int i = k; i < NUM_IT; ++i) {               // fallback: regen (k<64 only)
    const float ci = cf[i];
    const uint32_t kx = kxs[i], ky = kys[i];
#pragma unroll
    for (int j = 0; j < 4; ++j) {
      const uint32_t e = (uint32_t)(ebhw + j);
      uint32_t o0, o1;
      tf2x32(kx, ky, 0u, e,           o0, o1); float t0 = bits_to_normal(o0 ^ o1);
      tf2x32(kx, ky, 0u, e + HW,      o0, o1); float t1 = bits_to_normal(o0 ^ o1);
      tf2x32(kx, ky, 0u, e + 2u * HW, o0, o1); float t2 = bits_to_normal(o0 ^ o1);
      float mu = (t0 + t1 + t2) * (1.0f / 3.0f);
      float d0 = t0 - mu, d1 = t1 - mu, d2 = t2 - mu;
      float ss = fmaf(d0, d0, fmaf(d1, d1, d2 * d2));
      float gg = (0.070710678f * __builtin_amdgcn_rsqf(ss)) * ci;
      acc0[j] = fmaf(d0, gg, acc0[j]);
      acc1[j] = fmaf(d1, gg, acc1[j]);
    }
  }

  float4 r0, r1, r2;
  r0.x = acc0[0]; r0.y = acc0[1]; r0.z = acc0[2]; r0.w = acc0[3];
  r1.x = acc1[0]; r1.y = acc1[1]; r1.z = acc1[2]; r1.w = acc1[3];
  r2.x = -(acc0[0] + acc1[0]); r2.y = -(acc0[1] + acc1[1]);
  r2.z = -(acc0[2] + acc1[2]); r2.w = -(acc0[3] + acc1[3]);
  *(float4*)(out + ebhw)          = r0;
  *(float4*)(out + ebhw + HW)     = r1;
  *(float4*)(out + ebhw + 2 * HW) = r2;
}

extern "C" void kernel_launch(void* const* d_in, const int* in_sizes, int n_in,
                              void* d_out, int out_size, void* d_ws, size_t ws_size,
                              hipStream_t stream) {
  const float* imgs  = (const float*)d_in[0];
  const float* noise = (const float*)d_in[1];
  const float* wv    = (const float*)d_in[2];
  const float* bptr  = (const float*)d_in[3];
  float* out  = (float*)d_out;
  float* dots = (float*)d_ws;
  float* coef = dots + (NUM_IT + 1) * BATCH;
  uint32_t* ts32 = (uint32_t*)(dots + WS_FLOATS);

  // Adaptive staging: 4,014,080 B per staged unit (10-bit phase codes).
  // ws_size is constant across calls -> same k every launch -> graph-safe.
  size_t avail = ws_size > (size_t)WS_FLOATS * 4 ? ws_size - (size_t)WS_FLOATS * 4 : 0;
  int k = (int)(avail / ((size_t)IDX_PER_UB * 5 * BATCH));
  if (k > NUM_IT) k = NUM_IT;
  uint8_t* ts8 = (uint8_t*)ts32 + (size_t)k * BATCH * IDX_PER_UB * 4;

  hipMemsetAsync(dots, 0, (NUM_IT + 1) * BATCH * sizeof(float), stream);
  pass1_kernel<<<dim3(49, BATCH, 13), dim3(256), 0, stream>>>(imgs, noise, wv, dots, ts32, ts8, k);
  coef_kernel<<<dim3(1), dim3(64), 0, stream>>>(dots, bptr, coef);
  pass2_kernel<<<dim3(49, BATCH), dim3(256), 0, stream>>>(out, coef, ts32, ts8, k);
}

// Round 2
// 1474.795 us; speedup vs baseline: 1.3582x; 1.0627x over previous
//
#include <hip/hip_runtime.h>
#include <stdint.h>

#define NUM_IT 64
#define BATCH 64
#define HW 50176            // 224*224
#define CHW 150528          // 3*HW
#define SIGMA 0.05f

// ---- Circle staging -------------------------------------------------------
// Per pixel, the 3 zero-sum normalized channel perturbations are exactly
//   s_ch = QR8 * cos(phi - ch*2pi/3)   (one phase phi per pixel).
// Stored as 10 bits/px: 8-bit quantization of the smaller-magnitude
// coordinate m = min(|cos|,|sin|) (signed), a which-bit, and the sign of the
// other coordinate. Worst-case per-channel error QR8*sqrt(2)*step/2 = 2.26e-4.
// 64 units * 4.01 MB = 257 MB fits the ~289 MB workspace -> zero regen.
#define QR8 0.057735027f          // sigma*2/sqrt(3) = channel amplitude
#define ENC_SCALE 180.312f        // maps m in [-0.7071,0.7071] -> [0,255]
#define ENC_BIAS  127.5003f
#define DEC_STEP  5.5459533e-3f   // 1/ENC_SCALE
#define DEC_BIAS  (-0.70433384f)  // step/2 - 0.7071068 (midpoint decode)
#define IDX_PER_UB 12544
#define WS_FLOATS ((NUM_IT + 1) * BATCH + BATCH * NUM_IT)   // 8256 floats

// ---------------- Threefry-2x32, 20 rounds (JAX-exact) ----------------
__device__ __forceinline__ void tf2x32(uint32_t k0, uint32_t k1,
                                       uint32_t x0, uint32_t x1,
                                       uint32_t &o0, uint32_t &o1) {
  const uint32_t ks2 = k0 ^ k1 ^ 0x1BD11BDAu;
  x0 += k0; x1 += k1;
#define TF_R(r) { x0 += x1; x1 = __builtin_amdgcn_alignbit(x1, x1, 32u - (r)); x1 ^= x0; }
  TF_R(13) TF_R(15) TF_R(26) TF_R(6)
  x0 += k1;  x1 += ks2 + 1u;
  TF_R(17) TF_R(29) TF_R(16) TF_R(24)
  x0 += ks2; x1 += k0 + 2u;
  TF_R(13) TF_R(15) TF_R(26) TF_R(6)
  x0 += k0;  x1 += k1 + 3u;
  TF_R(17) TF_R(29) TF_R(16) TF_R(24)
  x0 += k1;  x1 += ks2 + 4u;
  TF_R(13) TF_R(15) TF_R(26) TF_R(6)
  x0 += ks2; x1 += k0 + 5u;
#undef TF_R
  o0 = x0; o1 = x1;
}

// bits -> uniform(-0.99999994, 1) -> sqrt(2)*erfinv (XLA/Giles f32 poly).
// log2-domain variant: z = fma(log2(1-s), -ln2, -2.5) folds the ln2 scaling
// and the -2.5 shift into one fma; the final *sqrt(2) is folded into the
// polynomial coefficients (<=1ulp coeff rounding -> |dt| ~1e-7, invisible
// under the 2.3e-4 quantization floor).
__device__ __forceinline__ float bits_to_normal(uint32_t bits) {
  const float LO = __uint_as_float(0xBF7FFFFFu);     // nextafter(-1,0)
  float u01 = __uint_as_float((bits >> 9) | 0x3f800000u) - 1.0f;  // [0,1)
  float u = fmaf(u01, 2.0f, LO);
  // 1 - round(u*u) is Sterbenz-exact; __fmul_rn blocks fp-contraction.
  float s = __fmul_rn(u, u);
  float l = __builtin_amdgcn_logf(1.0f - s);         // log2(1-s), <= 0
  float p;
  if (l > -7.2134752f) {                             // w = -ln2*l < 5
    float z = fmaf(l, -0.69314718f, -2.5f);          // = w - 2.5
    p = 3.9742706e-08f;                              // Giles coeffs * sqrt(2)
    p = fmaf(p, z, 4.8546625e-07f);
    p = fmaf(p, z, -4.9828231e-06f);
    p = fmaf(p, z, -6.2105327e-06f);
    p = fmaf(p, z, 3.0912001e-04f);
    p = fmaf(p, z, -1.7730352e-03f);
    p = fmaf(p, z, -5.9081342e-03f);
    p = fmaf(p, z, 3.4880277e-01f);
    p = fmaf(p, z, 2.1233141e+00f);
  } else {
    float w = l * -0.69314718f;
    float z = __builtin_amdgcn_sqrtf(w) - 3.0f;      // fast sqrt: z err ~4e-7
    p = -2.8314641e-04f;
    p = fmaf(p, z, 1.4276568e-04f);
    p = fmaf(p, z, 1.9082614e-03f);
    p = fmaf(p, z, -5.1950118e-03f);
    p = fmaf(p, z, 8.1168907e-03f);
    p = fmaf(p, z, -1.0779791e-02f);
    p = fmaf(p, z, 1.3348578e-02f);
    p = fmaf(p, z, 1.4165811e+00f);
    p = fmaf(p, z, 4.0064339e+00f);
  }
  return p * u;
}

__device__ __forceinline__ float clip01(float x) {
  return __builtin_amdgcn_fmed3f(x, 0.0f, 1.0f);     // 1 inst, finite inputs
}

// Wave64 sum via DPP (no LDS pipe, ~24cy vs ~200cy for 6 ds_swizzles).
// Canonical GCN sequence: row prefix (shr 1/2/4/8) -> lane15 of each row16
// holds row sum; bcast15 (rows 1,3) -> lane31/63 hold half sums; bcast31
// (rows 2,3) -> lane 63 holds the full 64-lane total.
template <int CTRL, int RM>
__device__ __forceinline__ float dpp_radd(float x) {
  int t = __builtin_amdgcn_update_dpp(0, __float_as_int(x), CTRL, RM, 0xF, true);
  return x + __int_as_float(t);
}
__device__ __forceinline__ float wave64_sum(float x) {
  x = dpp_radd<0x111, 0xF>(x);   // row_shr:1
  x = dpp_radd<0x112, 0xF>(x);   // row_shr:2
  x = dpp_radd<0x114, 0xF>(x);   // row_shr:4
  x = dpp_radd<0x118, 0xF>(x);   // row_shr:8
  x = dpp_radd<0x142, 0xA>(x);   // row_bcast:15 -> rows 1,3
  x = dpp_radd<0x143, 0xC>(x);   // row_bcast:31 -> rows 2,3
  return x;                      // lane 63 = total
}

// Pass 1: grid (49, BATCH, 13). Block z=g handles ii-units 5g..5g+4
// (unit 64 == prob2, in group 12). Stages 10-bit phase codes for unit<k.
__global__ __launch_bounds__(256) void pass1_kernel(
    const float* __restrict__ imgs, const float* __restrict__ noise,
    const float* __restrict__ wv, float* __restrict__ dots,
    uint32_t* __restrict__ ts32, uint8_t* __restrict__ ts8, const int k)
{
  const int g = blockIdx.z;
  const int b = blockIdx.y;
  __shared__ uint32_t kxs[5], kys[5];
  if (threadIdx.x < 5) {
    const int u = 5 * g + threadIdx.x;
    if (u < NUM_IT) {
      uint32_t kx, ky;
      tf2x32(0u, 42u, 0u, (uint32_t)u, kx, ky);
      kxs[threadIdx.x] = kx; kys[threadIdx.x] = ky;
    }
  }
  __syncthreads();

  const int idx  = blockIdx.x * 256 + threadIdx.x;        // 0..12543
  const int hw   = idx * 4;                               // 4 contiguous elems
  const int ebhw = b * CHW + hw;

  float ba[3][4], wc[3][4];
#pragma unroll
  for (int ch = 0; ch < 3; ++ch) {
    float4 iv = *(const float4*)(imgs  + ebhw + ch * HW);
    float4 nv = *(const float4*)(noise + ebhw + ch * HW);
    float4 wvv = *(const float4*)(wv   + hw   + ch * HW);
    ba[ch][0] = iv.x + nv.x; ba[ch][1] = iv.y + nv.y;
    ba[ch][2] = iv.z + nv.z; ba[ch][3] = iv.w + nv.w;
    wc[ch][0] = wvv.x; wc[ch][1] = wvv.y; wc[ch][2] = wvv.z; wc[ch][3] = wvv.w;
  }

#pragma unroll 1
  for (int u = 0; u < 5; ++u) {
    const int unit = 5 * g + u;       // 0..64; 64 == prob2
    if (unit > NUM_IT) break;
    float sum = 0.0f;
    if (unit == NUM_IT) {
#pragma unroll
      for (int ch = 0; ch < 3; ++ch)
#pragma unroll
        for (int j = 0; j < 4; ++j)
          sum = fmaf(clip01(ba[ch][j]), wc[ch][j], sum);
    } else {
      const uint32_t kx = kxs[u], ky = kys[u];
      uint32_t qa = 0, qb = 0;
#pragma unroll
      for (int j = 0; j < 4; ++j) {
        const uint32_t e = (uint32_t)(ebhw + j);
        uint32_t o0, o1;
        tf2x32(kx, ky, 0u, e,           o0, o1); float t0 = bits_to_normal(o0 ^ o1);
        tf2x32(kx, ky, 0u, e + HW,      o0, o1); float t1 = bits_to_normal(o0 ^ o1);
        tf2x32(kx, ky, 0u, e + 2u * HW, o0, o1); float t2 = bits_to_normal(o0 ^ o1);
        float mu = (t0 + t1 + t2) * (1.0f / 3.0f);
        float d0 = t0 - mu, d1 = t1 - mu, d2 = t2 - mu;
        float ss  = fmaf(d0, d0, fmaf(d1, d1, d2 * d2));    // = 2*var(ddof=1)
        float inv = __builtin_amdgcn_rsqf(ss);              // fast rsq ~1e-6
        float sc  = 0.070710678f * inv;                     // sigma*sqrt(2)
        sum = fmaf(clip01(fmaf(d0, sc, ba[0][j])), wc[0][j], sum);
        sum = fmaf(clip01(fmaf(d1, sc, ba[1][j])), wc[1][j], sum);
        sum = fmaf(clip01(fmaf(d2, sc, ba[2][j])), wc[2][j], sum);
        // encode: (cs,sn) = (cos phi, sin phi) of the pixel's phase
        float csc = 1.2247449f * inv;                       // sqrt(3/2)*inv
        float cs  = d0 * csc;
        float sn  = fmaf(d1, 1.4142136f * inv, 0.57735026f * cs);
        bool  wh  = __builtin_fabsf(sn) < __builtin_fabsf(cs);  // store sn?
        float m   = wh ? sn : cs;
        float oth = wh ? cs : sn;
        uint32_t q = (uint32_t)fmaf(m, ENC_SCALE, ENC_BIAS);    // cvt_u32 clamps neg
        uint32_t bits = q | (wh ? 256u : 0u) | (oth < 0.0f ? 512u : 0u);
        if (j < 3) qa |= bits << (10 * j);
        else       { qa |= bits << 30; qb = bits >> 2; }
      }
      if (unit < k) {
        const size_t base = (size_t)(unit * BATCH + b) * IDX_PER_UB + idx;
        ts32[base] = qa;
        ts8[base]  = (uint8_t)qb;
      }
    }
    sum = wave64_sum(sum);
    if ((threadIdx.x & 63) == 63) atomicAdd(&dots[unit * BATCH + b], sum);
  }
}

__global__ void coef_kernel(const float* __restrict__ dots,
                            const float* __restrict__ bptr,
                            float* __restrict__ coef) {
  const int b = threadIdx.x;  // 64 threads
  const float bias = bptr[0];
  const float p2 = 1.0f / (1.0f + expf(-(dots[NUM_IT * BATCH + b] + bias)));
  float nc = 0.0f;
  for (int i = 0; i < NUM_IT; ++i) {
    float ap = 1.0f / (1.0f + expf(-(dots[i * BATCH + b] + bias)));
    float d = p2 - ap;
    nc += d * d;
  }
  const float inv = 1.0f / ((float)NUM_IT * SIGMA * (sqrtf(nc) + 1e-10f));
  for (int i = 0; i < NUM_IT; ++i) {
    float ap = 1.0f / (1.0f + expf(-(dots[i * BATCH + b] + bias)));
    float d = p2 - ap;
    coef[b * NUM_IT + i] = d * inv;
  }
}

// Pass 2: grid (49, BATCH). Single writer per output element: decode all k
// staged units, regen any i>=k (expected none), plain float4 stores, no
// atomics, no out memset. ch2 = -(ch0+ch1).
__global__ __launch_bounds__(256) void pass2_kernel(
    float* __restrict__ out, const float* __restrict__ coef,
    const uint32_t* __restrict__ ts32, const uint8_t* __restrict__ ts8,
    const int k)
{
  const int b = blockIdx.y;
  __shared__ float cf[NUM_IT];
  __shared__ uint32_t kxs[NUM_IT], kys[NUM_IT];
  if (threadIdx.x < NUM_IT) {
    const int i = threadIdx.x;
    cf[i] = coef[b * NUM_IT + i];
    if (i >= k) {
      uint32_t kx, ky;
      tf2x32(0u, 42u, 0u, (uint32_t)i, kx, ky);
      kxs[i] = kx; kys[i] = ky;
    }
  }
  __syncthreads();

  const int idx  = blockIdx.x * 256 + threadIdx.x;
  const int hw   = idx * 4;
  const int ebhw = b * CHW + hw;
  float acc0[4] = {0.f, 0.f, 0.f, 0.f};
  float acc1[4] = {0.f, 0.f, 0.f, 0.f};

#pragma unroll 1
  for (int i = 0; i < k; ++i) {                    // staged units: decode
    const float ci = cf[i];
    const size_t base = (size_t)(i * BATCH + b) * IDX_PER_UB + idx;
    const uint32_t wa = ts32[base];
    const uint32_t wb = ts8[base];
#pragma unroll
    for (int j = 0; j < 4; ++j) {
      uint32_t bits = (j < 3) ? ((wa >> (10 * j)) & 1023u)
                              : ((wa >> 30) | (wb << 2));
      float m = fmaf((float)(bits & 255u), DEC_STEP, DEC_BIAS);
      m = __builtin_amdgcn_fmed3f(m, -0.7071068f, 0.7071068f);
      float o = __builtin_amdgcn_sqrtf(fmaf(-m, m, 1.0f));
      o = (bits & 512u) ? -o : o;
      const bool wh = (bits & 256u) != 0u;
      float cc = wh ? o : m;
      float sv = wh ? m : o;
      float s0 = QR8 * cc;
      float s1 = fmaf(sv, 0.05f, -0.5f * s0);      // QR8*sqrt(3)/2 == sigma
      acc0[j] = fmaf(s0, ci, acc0[j]);
      acc1[j] = fmaf(s1, ci, acc1[j]);
    }
  }
#pragma unroll 1
  for (int i = k; i < NUM_IT; ++i) {               // fallback: regen (k<64 only)
    const float ci = cf[i];
    const uint32_t kx = kxs[i], ky = kys[i];
#pragma unroll
    for (int j = 0; j < 4; ++j) {
      const uint32_t e = (uint32_t)(ebhw + j);
      uint32_t o0, o1;
      tf2x32(kx, ky, 0u, e,           o0, o1); float t0 = bits_to_normal(o0 ^ o1);
      tf2x32(kx, ky, 0u, e + HW,      o0, o1); float t1 = bits_to_normal(o0 ^ o1);
      tf2x32(kx, ky, 0u, e + 2u * HW, o0, o1); float t2 = bits_to_normal(o0 ^ o1);
      float mu = (t0 + t1 + t2) * (1.0f / 3.0f);
      float d0 = t0 - mu, d1 = t1 - mu, d2 = t2 - mu;
      float ss = fmaf(d0, d0, fmaf(d1, d1, d2 * d2));
      float gg = (0.070710678f * __builtin_amdgcn_rsqf(ss)) * ci;
      acc0[j] = fmaf(d0, gg, acc0[j]);
      acc1[j] = fmaf(d1, gg, acc1[j]);
    }
  }

  float4 r0, r1, r2;
  r0.x = acc0[0]; r0.y = acc0[1]; r0.z = acc0[2]; r0.w = acc0[3];
  r1.x = acc1[0]; r1.y = acc1[1]; r1.z = acc1[2]; r1.w = acc1[3];
  r2.x = -(acc0[0] + acc1[0]); r2.y = -(acc0[1] + acc1[1]);
  r2.z = -(acc0[2] + acc1[2]); r2.w = -(acc0[3] + acc1[3]);
  *(float4*)(out + ebhw)          = r0;
  *(float4*)(out + ebhw + HW)     = r1;
  *(float4*)(out + ebhw + 2 * HW) = r2;
}

extern "C" void kernel_launch(void* const* d_in, const int* in_sizes, int n_in,
                              void* d_out, int out_size, void* d_ws, size_t ws_size,
                              hipStream_t stream) {
  const float* imgs  = (const float*)d_in[0];
  const float* noise = (const float*)d_in[1];
  const float* wv    = (const float*)d_in[2];
  const float* bptr  = (const float*)d_in[3];
  float* out  = (float*)d_out;
  float* dots = (float*)d_ws;
  float* coef = dots + (NUM_IT + 1) * BATCH;
  uint32_t* ts32 = (uint32_t*)(dots + WS_FLOATS);

  // Adaptive staging: 4,014,080 B per staged unit (10-bit phase codes).
  // ws_size is constant across calls -> same k every launch -> graph-safe.
  size_t avail = ws_size > (size_t)WS_FLOATS * 4 ? ws_size - (size_t)WS_FLOATS * 4 : 0;
  int k = (int)(avail / ((size_t)IDX_PER_UB * 5 * BATCH));
  if (k > NUM_IT) k = NUM_IT;
  uint8_t* ts8 = (uint8_t*)ts32 + (size_t)k * BATCH * IDX_PER_UB * 4;

  hipMemsetAsync(dots, 0, (NUM_IT + 1) * BATCH * sizeof(float), stream);
  pass1_kernel<<<dim3(49, BATCH, 13), dim3(256), 0, stream>>>(imgs, noise, wv, dots, ts32, ts8, k);
  coef_kernel<<<dim3(1), dim3(64), 0, stream>>>(dots, bptr, coef);
  pass2_kernel<<<dim3(49, BATCH), dim3(256), 0, stream>>>(out, coef, ts32, ts8, k);
}

// Round 3
// 1451.019 us; speedup vs baseline: 1.3805x; 1.0164x over previous
//
#include <hip/hip_runtime.h>
#include <stdint.h>

#define NUM_IT 64
#define BATCH 64
#define HW 50176            // 224*224
#define CHW 150528          // 3*HW
#define SIGMA 0.05f

// ---- Circle staging -------------------------------------------------------
// Per pixel, the 3 zero-sum normalized channel perturbations are exactly
//   s_ch = QR8 * cos(phi - ch*2pi/3)   (one phase phi per pixel).
// Stored as 10 bits/px: 8-bit quantization of the smaller-magnitude
// coordinate m = min(|cos|,|sin|) (signed), a which-bit, and the sign of the
// other coordinate. Worst-case per-channel error QR8*sqrt(2)*step/2 = 2.26e-4.
// 64 units * 4.01 MB = 257 MB fits the ~289 MB workspace -> zero regen.
#define QR8 0.057735027f          // sigma*2/sqrt(3) = channel amplitude
#define ENC_SCALE 180.312f        // maps m in [-0.7071,0.7071] -> [0,255]
#define ENC_BIAS  127.5003f
#define DEC_STEP  5.5459533e-3f   // 1/ENC_SCALE
#define DEC_BIAS  (-0.70433384f)  // step/2 - 0.7071068 (midpoint decode)
#define IDX_PER_UB 12544
#define WS_FLOATS ((NUM_IT + 1) * BATCH + BATCH * NUM_IT)   // 8256 floats

// ---------------- Threefry-2x32, 20 rounds (JAX-exact) ----------------
__device__ __forceinline__ void tf2x32(uint32_t k0, uint32_t k1,
                                       uint32_t x0, uint32_t x1,
                                       uint32_t &o0, uint32_t &o1) {
  const uint32_t ks2 = k0 ^ k1 ^ 0x1BD11BDAu;
  x0 += k0; x1 += k1;
#define TF_R(r) { x0 += x1; x1 = __builtin_amdgcn_alignbit(x1, x1, 32u - (r)); x1 ^= x0; }
  TF_R(13) TF_R(15) TF_R(26) TF_R(6)
  x0 += k1;  x1 += ks2 + 1u;
  TF_R(17) TF_R(29) TF_R(16) TF_R(24)
  x0 += ks2; x1 += k0 + 2u;
  TF_R(13) TF_R(15) TF_R(26) TF_R(6)
  x0 += k0;  x1 += k1 + 3u;
  TF_R(17) TF_R(29) TF_R(16) TF_R(24)
  x0 += k1;  x1 += ks2 + 4u;
  TF_R(13) TF_R(15) TF_R(26) TF_R(6)
  x0 += ks2; x1 += k0 + 5u;
#undef TF_R
  o0 = x0; o1 = x1;
}

// ---- Compile-time per-unit keys: tf2x32(0,42,0,u) is a pure constant. -----
// Embedded as a __constant__ table -> wave-uniform s_load, no LDS, no
// __syncthreads, no per-unit lgkmcnt stall, keys live in SGPRs.
struct alignas(8) KPair { uint32_t x, y; };
constexpr uint32_t kr_rotl(uint32_t v, int r) {
  return (v << r) | (v >> (32 - r));
}
constexpr KPair tf_key(uint32_t u) {
  uint32_t k0 = 0u, k1 = 42u;
  uint32_t ks2 = k0 ^ k1 ^ 0x1BD11BDAu;
  uint32_t x0 = 0u + k0, x1 = u + k1;
#define TFC_R(r) { x0 += x1; x1 = kr_rotl(x1, r); x1 ^= x0; }
  TFC_R(13) TFC_R(15) TFC_R(26) TFC_R(6)
  x0 += k1;  x1 += ks2 + 1u;
  TFC_R(17) TFC_R(29) TFC_R(16) TFC_R(24)
  x0 += ks2; x1 += k0 + 2u;
  TFC_R(13) TFC_R(15) TFC_R(26) TFC_R(6)
  x0 += k0;  x1 += k1 + 3u;
  TFC_R(17) TFC_R(29) TFC_R(16) TFC_R(24)
  x0 += k1;  x1 += ks2 + 4u;
  TFC_R(13) TFC_R(15) TFC_R(26) TFC_R(6)
  x0 += ks2; x1 += k0 + 5u;
#undef TFC_R
  return KPair{x0, x1};
}
#define KT4(n)  tf_key(n), tf_key((n)+1), tf_key((n)+2), tf_key((n)+3)
#define KT16(n) KT4(n), KT4((n)+4), KT4((n)+8), KT4((n)+12)
__device__ __constant__ KPair KT[65] = { KT16(0), KT16(16), KT16(32), KT16(48),
                                         tf_key(64) };

// bits -> uniform(-0.99999994, 1) -> sqrt(2)*erfinv (XLA/Giles f32 poly).
// log2-domain variant: z = fma(log2(1-s), -ln2, -2.5) folds the ln2 scaling
// and the -2.5 shift into one fma; the final *sqrt(2) is folded into the
// polynomial coefficients (<=1ulp coeff rounding -> |dt| ~1e-7, invisible
// under the 2.3e-4 quantization floor).
__device__ __forceinline__ float bits_to_normal(uint32_t bits) {
  const float LO = __uint_as_float(0xBF7FFFFFu);     // nextafter(-1,0)
  float u01 = __uint_as_float((bits >> 9) | 0x3f800000u) - 1.0f;  // [0,1)
  float u = fmaf(u01, 2.0f, LO);
  // 1 - round(u*u) is Sterbenz-exact; __fmul_rn blocks fp-contraction.
  float s = __fmul_rn(u, u);
  float l = __builtin_amdgcn_logf(1.0f - s);         // log2(1-s), <= 0
  float p;
  if (l > -7.2134752f) {                             // w = -ln2*l < 5
    float z = fmaf(l, -0.69314718f, -2.5f);          // = w - 2.5
    p = 3.9742706e-08f;                              // Giles coeffs * sqrt(2)
    p = fmaf(p, z, 4.8546625e-07f);
    p = fmaf(p, z, -4.9828231e-06f);
    p = fmaf(p, z, -6.2105327e-06f);
    p = fmaf(p, z, 3.0912001e-04f);
    p = fmaf(p, z, -1.7730352e-03f);
    p = fmaf(p, z, -5.9081342e-03f);
    p = fmaf(p, z, 3.4880277e-01f);
    p = fmaf(p, z, 2.1233141e+00f);
  } else {
    float w = l * -0.69314718f;
    float z = __builtin_amdgcn_sqrtf(w) - 3.0f;      // fast sqrt: z err ~4e-7
    p = -2.8314641e-04f;
    p = fmaf(p, z, 1.4276568e-04f);
    p = fmaf(p, z, 1.9082614e-03f);
    p = fmaf(p, z, -5.1950118e-03f);
    p = fmaf(p, z, 8.1168907e-03f);
    p = fmaf(p, z, -1.0779791e-02f);
    p = fmaf(p, z, 1.3348578e-02f);
    p = fmaf(p, z, 1.4165811e+00f);
    p = fmaf(p, z, 4.0064339e+00f);
  }
  return p * u;
}

__device__ __forceinline__ float clip01(float x) {
  return __builtin_amdgcn_fmed3f(x, 0.0f, 1.0f);     // 1 inst, finite inputs
}

// Wave64 sum via DPP (no LDS pipe, ~24cy vs ~200cy for 6 ds_swizzles).
template <int CTRL, int RM>
__device__ __forceinline__ float dpp_radd(float x) {
  int t = __builtin_amdgcn_update_dpp(0, __float_as_int(x), CTRL, RM, 0xF, true);
  return x + __int_as_float(t);
}
__device__ __forceinline__ float wave64_sum(float x) {
  x = dpp_radd<0x111, 0xF>(x);   // row_shr:1
  x = dpp_radd<0x112, 0xF>(x);   // row_shr:2
  x = dpp_radd<0x114, 0xF>(x);   // row_shr:4
  x = dpp_radd<0x118, 0xF>(x);   // row_shr:8
  x = dpp_radd<0x142, 0xA>(x);   // row_bcast:15 -> rows 1,3
  x = dpp_radd<0x143, 0xC>(x);   // row_bcast:31 -> rows 2,3
  return x;                      // lane 63 = total
}

// Pass 1: grid (49, BATCH, 13). Block z=g handles ii-units 5g..5g+4
// (unit 64 == prob2, in group 12). Stages 10-bit phase codes for unit<k.
// No LDS: per-unit keys come from the __constant__ KT table (uniform index).
__global__ __launch_bounds__(256) void pass1_kernel(
    const float* __restrict__ imgs, const float* __restrict__ noise,
    const float* __restrict__ wv, float* __restrict__ dots,
    uint32_t* __restrict__ ts32, uint8_t* __restrict__ ts8, const int k)
{
  const int g = blockIdx.z;
  const int b = blockIdx.y;

  const int idx  = blockIdx.x * 256 + threadIdx.x;        // 0..12543
  const int hw   = idx * 4;                               // 4 contiguous elems
  const int ebhw = b * CHW + hw;

  float ba[3][4], wc[3][4];
#pragma unroll
  for (int ch = 0; ch < 3; ++ch) {
    float4 iv = *(const float4*)(imgs  + ebhw + ch * HW);
    float4 nv = *(const float4*)(noise + ebhw + ch * HW);
    float4 wvv = *(const float4*)(wv   + hw   + ch * HW);
    ba[ch][0] = iv.x + nv.x; ba[ch][1] = iv.y + nv.y;
    ba[ch][2] = iv.z + nv.z; ba[ch][3] = iv.w + nv.w;
    wc[ch][0] = wvv.x; wc[ch][1] = wvv.y; wc[ch][2] = wvv.z; wc[ch][3] = wvv.w;
  }

#pragma unroll 1
  for (int u = 0; u < 5; ++u) {
    const int unit = 5 * g + u;       // 0..64; 64 == prob2
    if (unit > NUM_IT) break;
    float sum = 0.0f;
    if (unit == NUM_IT) {
#pragma unroll
      for (int ch = 0; ch < 3; ++ch)
#pragma unroll
        for (int j = 0; j < 4; ++j)
          sum = fmaf(clip01(ba[ch][j]), wc[ch][j], sum);
    } else {
      const uint32_t kx = KT[unit].x, ky = KT[unit].y;    // s_load, SGPRs
      uint32_t qa = 0, qb = 0;
#pragma unroll
      for (int j = 0; j < 4; ++j) {
        const uint32_t e = (uint32_t)(ebhw + j);
        uint32_t o0, o1;
        tf2x32(kx, ky, 0u, e,           o0, o1); float t0 = bits_to_normal(o0 ^ o1);
        tf2x32(kx, ky, 0u, e + HW,      o0, o1); float t1 = bits_to_normal(o0 ^ o1);
        tf2x32(kx, ky, 0u, e + 2u * HW, o0, o1); float t2 = bits_to_normal(o0 ^ o1);
        float mu = (t0 + t1 + t2) * (1.0f / 3.0f);
        float d0 = t0 - mu, d1 = t1 - mu, d2 = t2 - mu;
        float ss  = fmaf(d0, d0, fmaf(d1, d1, d2 * d2));    // = 2*var(ddof=1)
        float inv = __builtin_amdgcn_rsqf(ss);              // fast rsq ~1e-6
        float sc  = 0.070710678f * inv;                     // sigma*sqrt(2)
        sum = fmaf(clip01(fmaf(d0, sc, ba[0][j])), wc[0][j], sum);
        sum = fmaf(clip01(fmaf(d1, sc, ba[1][j])), wc[1][j], sum);
        sum = fmaf(clip01(fmaf(d2, sc, ba[2][j])), wc[2][j], sum);
        // encode: (cs,sn) = (cos phi, sin phi) of the pixel's phase
        float csc = 1.2247449f * inv;                       // sqrt(3/2)*inv
        float cs  = d0 * csc;
        float sn  = fmaf(d1, 1.4142136f * inv, 0.57735026f * cs);
        bool  wh  = __builtin_fabsf(sn) < __builtin_fabsf(cs);  // store sn?
        float m   = wh ? sn : cs;
        float oth = wh ? cs : sn;
        uint32_t q = (uint32_t)fmaf(m, ENC_SCALE, ENC_BIAS);    // cvt_u32 clamps neg
        uint32_t bits = q | (wh ? 256u : 0u) | (oth < 0.0f ? 512u : 0u);
        if (j < 3) qa |= bits << (10 * j);
        else       { qa |= bits << 30; qb = bits >> 2; }
      }
      if (unit < k) {
        const size_t base = (size_t)(unit * BATCH + b) * IDX_PER_UB + idx;
        ts32[base] = qa;
        ts8[base]  = (uint8_t)qb;
      }
    }
    sum = wave64_sum(sum);
    if ((threadIdx.x & 63) == 63) atomicAdd(&dots[unit * BATCH + b], sum);
  }
}

__global__ void coef_kernel(const float* __restrict__ dots,
                            const float* __restrict__ bptr,
                            float* __restrict__ coef) {
  const int b = threadIdx.x;  // 64 threads
  const float bias = bptr[0];
  const float p2 = 1.0f / (1.0f + expf(-(dots[NUM_IT * BATCH + b] + bias)));
  float nc = 0.0f;
  for (int i = 0; i < NUM_IT; ++i) {
    float ap = 1.0f / (1.0f + expf(-(dots[i * BATCH + b] + bias)));
    float d = p2 - ap;
    nc += d * d;
  }
  const float inv = 1.0f / ((float)NUM_IT * SIGMA * (sqrtf(nc) + 1e-10f));
  for (int i = 0; i < NUM_IT; ++i) {
    float ap = 1.0f / (1.0f + expf(-(dots[i * BATCH + b] + bias)));
    float d = p2 - ap;
    coef[b * NUM_IT + i] = d * inv;
  }
}

// Pass 2: grid (49, BATCH). Single writer per output element: decode all k
// staged units, regen any i>=k (expected none), plain float4 stores, no
// atomics, no out memset. ch2 = -(ch0+ch1).
__global__ __launch_bounds__(256) void pass2_kernel(
    float* __restrict__ out, const float* __restrict__ coef,
    const uint32_t* __restrict__ ts32, const uint8_t* __restrict__ ts8,
    const int k)
{
  const int b = blockIdx.y;
  __shared__ float cf[NUM_IT];
  if (threadIdx.x < NUM_IT)
    cf[threadIdx.x] = coef[b * NUM_IT + threadIdx.x];
  __syncthreads();

  const int idx  = blockIdx.x * 256 + threadIdx.x;
  const int hw   = idx * 4;
  const int ebhw = b * CHW + hw;
  float acc0[4] = {0.f, 0.f, 0.f, 0.f};
  float acc1[4] = {0.f, 0.f, 0.f, 0.f};

#pragma unroll 1
  for (int i = 0; i < k; ++i) {                    // staged units: decode
    const float ci = cf[i];
    const size_t base = (size_t)(i * BATCH + b) * IDX_PER_UB + idx;
    const uint32_t wa = ts32[base];
    const uint32_t wb = ts8[base];
#pragma unroll
    for (int j = 0; j < 4; ++j) {
      uint32_t bits = (j < 3) ? ((wa >> (10 * j)) & 1023u)
                              : ((wa >> 30) | (wb << 2));
      float m = fmaf((float)(bits & 255u), DEC_STEP, DEC_BIAS);
      m = __builtin_amdgcn_fmed3f(m, -0.7071068f, 0.7071068f);
      float o = __builtin_amdgcn_sqrtf(fmaf(-m, m, 1.0f));
      o = (bits & 512u) ? -o : o;
      const bool wh = (bits & 256u) != 0u;
      float cc = wh ? o : m;
      float sv = wh ? m : o;
      float s0 = QR8 * cc;
      float s1 = fmaf(sv, 0.05f, -0.5f * s0);      // QR8*sqrt(3)/2 == sigma
      acc0[j] = fmaf(s0, ci, acc0[j]);
      acc1[j] = fmaf(s1, ci, acc1[j]);
    }
  }
#pragma unroll 1
  for (int i = k; i < NUM_IT; ++i) {               // fallback: regen (k<64 only)
    const float ci = cf[i];
    const uint32_t kx = KT[i].x, ky = KT[i].y;
#pragma unroll
    for (int j = 0; j < 4; ++j) {
      const uint32_t e = (uint32_t)(ebhw + j);
      uint32_t o0, o1;
      tf2x32(kx, ky, 0u, e,           o0, o1); float t0 = bits_to_normal(o0 ^ o1);
      tf2x32(kx, ky, 0u, e + HW,      o0, o1); float t1 = bits_to_normal(o0 ^ o1);
      tf2x32(kx, ky, 0u, e + 2u * HW, o0, o1); float t2 = bits_to_normal(o0 ^ o1);
      float mu = (t0 + t1 + t2) * (1.0f / 3.0f);
      float d0 = t0 - mu, d1 = t1 - mu, d2 = t2 - mu;
      float ss = fmaf(d0, d0, fmaf(d1, d1, d2 * d2));
      float gg = (0.070710678f * __builtin_amdgcn_rsqf(ss)) * ci;
      acc0[j] = fmaf(d0, gg, acc0[j]);
      acc1[j] = fmaf(d1, gg, acc1[j]);
    }
  }

  float4 r0, r1, r2;
  r0.x = acc0[0]; r0.y = acc0[1]; r0.z = acc0[2]; r0.w = acc0[3];
  r1.x = acc1[0]; r1.y = acc1[1]; r1.z = acc1[2]; r1.w = acc1[3];
  r2.x = -(acc0[0] + acc1[0]); r2.y = -(acc0[1] + acc1[1]);
  r2.z = -(acc0[2] + acc1[2]); r2.w = -(acc0[3] + acc1[3]);
  *(float4*)(out + ebhw)          = r0;
  *(float4*)(out + ebhw + HW)     = r1;
  *(float4*)(out + ebhw + 2 * HW) = r2;
}

extern "C" void kernel_launch(void* const* d_in, const int* in_sizes, int n_in,
                              void* d_out, int out_size, void* d_ws, size_t ws_size,
                              hipStream_t stream) {
  const float* imgs  = (const float*)d_in[0];
  const float* noise = (const float*)d_in[1];
  const float* wv    = (const float*)d_in[2];
  const float* bptr  = (const float*)d_in[3];
  float* out  = (float*)d_out;
  float* dots = (float*)d_ws;
  float* coef = dots + (NUM_IT + 1) * BATCH;
  uint32_t* ts32 = (uint32_t*)(dots + WS_FLOATS);

  // Adaptive staging: 4,014,080 B per staged unit (10-bit phase codes).
  // ws_size is constant across calls -> same k every launch -> graph-safe.
  size_t avail = ws_size > (size_t)WS_FLOATS * 4 ? ws_size - (size_t)WS_FLOATS * 4 : 0;
  int k = (int)(avail / ((size_t)IDX_PER_UB * 5 * BATCH));
  if (k > NUM_IT) k = NUM_IT;
  uint8_t* ts8 = (uint8_t*)ts32 + (size_t)k * BATCH * IDX_PER_UB * 4;

  hipMemsetAsync(dots, 0, (NUM_IT + 1) * BATCH * sizeof(float), stream);
  pass1_kernel<<<dim3(49, BATCH, 13), dim3(256), 0, stream>>>(imgs, noise, wv, dots, ts32, ts8, k);
  coef_kernel<<<dim3(1), dim3(64), 0, stream>>>(dots, bptr, coef);
  pass2_kernel<<<dim3(49, BATCH), dim3(256), 0, stream>>>(out, coef, ts32, ts8, k);
}